// Round 15
// baseline (203.129 us; speedup 1.0000x reference)
//
#include <hip/hip_runtime.h>
#include <stdint.h>

#define DEV __device__ __forceinline__

typedef __bf16 bf16x8 __attribute__((ext_vector_type(8)));
typedef float f32x2 __attribute__((ext_vector_type(2)));
typedef float f32x4 __attribute__((ext_vector_type(4)));
typedef float f32x16 __attribute__((ext_vector_type(16)));

DEV uint16_t f2bf(float f) {
  union { float f; uint32_t u; } v; v.f = f;
  return (uint16_t)((v.u + 0x7FFFu + ((v.u >> 16) & 1u)) >> 16);
}

DEV f32x2 pkadd(f32x2 a, f32x2 b) {
  f32x2 d;
  asm("v_pk_add_f32 %0, %1, %2" : "=v"(d) : "v"(a), "v"(b));
  return d;
}

// async global->LDS, 16B per lane; LDS dest must be wave-uniform base
#define GLD_LDS(gsrc, ldst)                                                   \
  __builtin_amdgcn_global_load_lds(                                           \
      (__attribute__((address_space(1))) void*)(void*)(gsrc),                 \
      (__attribute__((address_space(3))) void*)(ldst), 16, 0, 0)

// ---------------- fused prep: x->bf16 + both W transposes ----------------
__global__ __launch_bounds__(256) void k_prep(const float* __restrict__ x,
                                              const float* __restrict__ Wqkv,
                                              const float* __restrict__ Wproj,
                                              uint16_t* __restrict__ xb,
                                              uint16_t* __restrict__ wqkvt,
                                              uint16_t* __restrict__ wprojt) {
  __shared__ float tile[32][33];
  int bid = blockIdx.x;
  if (bid < 4096) {
    int i = bid * 256 + threadIdx.x;
    const float4* p = (const float4*)x;
    float4 a = p[i * 2], b = p[i * 2 + 1];
    union { uint16_t s[8]; uint4 v; } o;
    o.s[0] = f2bf(a.x); o.s[1] = f2bf(a.y); o.s[2] = f2bf(a.z); o.s[3] = f2bf(a.w);
    o.s[4] = f2bf(b.x); o.s[5] = f2bf(b.y); o.s[6] = f2bf(b.z); o.s[7] = f2bf(b.w);
    ((uint4*)xb)[i] = o.v;
    return;
  }
  const float* in;
  uint16_t* out;
  int n0, k0, Ncols;
  if (bid < 7168) {
    int local = bid - 4096;
    in = Wqkv; out = wqkvt; Ncols = 3072;
    n0 = (local % 96) * 32; k0 = (local / 96) * 32;
  } else {
    int local = bid - 7168;
    in = Wproj; out = wprojt; Ncols = 1024;
    n0 = (local % 32) * 32; k0 = (local / 32) * 32;
  }
  int tx = threadIdx.x & 31, ty = threadIdx.x >> 5;  // 8 rows of 32
  #pragma unroll
  for (int r = ty; r < 32; r += 8)
    tile[r][tx] = in[(size_t)(k0 + r) * Ncols + n0 + tx];
  __syncthreads();
  #pragma unroll
  for (int r = ty; r < 32; r += 8)
    out[(size_t)(n0 + r) * 1024 + k0 + tx] = f2bf(tile[tx][r]);
}

// ---------------- bf16 GEMM: C[M,N] = A[M,K=1024] * BT[N,K]^T + bias ----------------
// (R8 structure) 2-phase double-buffered: stage ks+1 BEFORE compute of ks;
// ONE __syncthreads per K-step. 2-D grid.
// MODE 0 epilogue: Q (pre-scaled) / K written via LDS-bounce -> fully-coalesced
// uint4 stores (each tile's Q/K region is [128 rows x 64 d] contiguous per head);
// V FRAGMENT-MAJOR vtb[bh*131072 + kt*4096 + f*512 + lane*8 + e] (uint2 stores).
template <int MODE>
__global__ __launch_bounds__(256) void k_gemm(
    const uint16_t* __restrict__ A, const uint16_t* __restrict__ BT,
    const float* __restrict__ bias, float* __restrict__ fout, int Ndim,
    uint16_t* __restrict__ qb, uint16_t* __restrict__ kb,
    uint16_t* __restrict__ vtb) {
  __shared__ uint16_t As[2][128 * 32];
  __shared__ uint16_t Bs[2][128 * 32];
  const int K = 1024;
  int tid = threadIdx.x;
  int lane = tid & 63, wid = tid >> 6;
  int lg = lane >> 4, lr = lane & 15;
  int wr = wid >> 1, wc = wid & 1;
  int bm = blockIdx.x, bn = blockIdx.y;

  int c0 = tid, c1 = tid + 256;
  int r0 = c0 >> 2, sl0 = (c0 & 3) ^ (r0 & 3);
  int r1 = c1 >> 2, sl1 = (c1 & 3) ^ (r1 & 3);
  const uint16_t* gA0 = A + (size_t)(bm * 128 + r0) * K + sl0 * 8;
  const uint16_t* gA1 = A + (size_t)(bm * 128 + r1) * K + sl1 * 8;
  const uint16_t* gB0 = BT + (size_t)(bn * 128 + r0) * K + sl0 * 8;
  const uint16_t* gB1 = BT + (size_t)(bn * 128 + r1) * K + sl1 * 8;

  uint32_t aoff[4], boff[4];
  #pragma unroll
  for (int i = 0; i < 4; ++i) {
    int rowa = wr * 64 + i * 16 + lr;
    aoff[i] = rowa * 64 + ((lg ^ (rowa & 3)) << 4);
    int rowb = wc * 64 + i * 16 + lr;
    boff[i] = rowb * 64 + ((lg ^ (rowb & 3)) << 4);
  }

  f32x4 acc[4][4] = {};

  auto stageg = [&](int buf) {
    GLD_LDS(gA0, &As[buf][wid * 512]);
    GLD_LDS(gA1, &As[buf][2048 + wid * 512]);
    GLD_LDS(gB0, &Bs[buf][wid * 512]);
    GLD_LDS(gB1, &Bs[buf][2048 + wid * 512]);
    gA0 += 32; gA1 += 32; gB0 += 32; gB1 += 32;
  };

  auto gbody = [&](int cur, bool dostage) {
    if (dostage) stageg(cur ^ 1);
    const char* Ab = (const char*)As + cur * 8192;
    const char* Bb = (const char*)Bs + cur * 8192;
    bf16x8 af[4], bfv[4];
    #pragma unroll
    for (int i = 0; i < 4; ++i) af[i] = *(const bf16x8*)(Ab + aoff[i]);
    #pragma unroll
    for (int j = 0; j < 4; ++j) bfv[j] = *(const bf16x8*)(Bb + boff[j]);
    __builtin_amdgcn_s_setprio(1);
    #pragma unroll
    for (int i = 0; i < 4; ++i)
      #pragma unroll
      for (int j = 0; j < 4; ++j)
        acc[i][j] = __builtin_amdgcn_mfma_f32_16x16x32_bf16(af[i], bfv[j],
                                                            acc[i][j], 0, 0, 0);
    __builtin_amdgcn_s_setprio(0);
    __syncthreads();
  };

  stageg(0);
  __syncthreads();
  for (int ks = 0; ks < 30; ks += 2) {
    gbody(0, true);
    gbody(1, true);
  }
  gbody(0, true);
  gbody(1, false);

  int m0 = bm * 128 + wr * 64;
  int n0 = bn * 128 + wc * 64;
  if (MODE == 1) {
    #pragma unroll
    for (int i = 0; i < 4; ++i) {
      int row = m0 + i * 16 + lg * 4;
      #pragma unroll
      for (int j = 0; j < 4; ++j) {
        int col = n0 + j * 16 + lr;
        float bv = bias[col];
        #pragma unroll
        for (int r = 0; r < 4; ++r)
          fout[(size_t)(row + r) * Ndim + col] = acc[i][j][r] + bv;
      }
    }
  } else {
    const float QSC = 0.18033688011112042f;  // 1/sqrt(64) * log2(e)
    int which = bn >> 3;  // 0=Q 1=K 2=V (tile spans a single operand)
    if (which == 2) {
      // fragment-major V (R12-proven): tile t>>6, frag (d>>5)*4+((t>>4)&3),
      // lane ((t>>3)&1)*32+(d&31), elems (t&7)+r (contiguous -> uint2)
      #pragma unroll
      for (int i = 0; i < 4; ++i) {
        int rowb = m0 + i * 16 + lg * 4;
        int b = rowb >> 11, t = rowb & 2047;
        #pragma unroll
        for (int j = 0; j < 4; ++j) {
          int colb = n0 + j * 16 + lr;
          int d = colb & 63;
          float bv = bias[colb];
          size_t bh = (size_t)(b * 16 + ((colb & 1023) >> 6));
          union { uint16_t s[4]; uint2 v; } pk;
          #pragma unroll
          for (int r = 0; r < 4; ++r) pk.s[r] = f2bf(acc[i][j][r] + bv);
          size_t vidx = bh * 131072 + (size_t)(t >> 6) * 4096 +
                        (size_t)((d >> 5) * 4 + ((t >> 4) & 3)) * 512 +
                        (size_t)((((t >> 3) & 1) * 32 + (d & 31)) * 8) + (t & 7);
          *(uint2*)&vtb[vidx] = pk.v;
        }
      }
    } else {
      // Q/K LDS-bounce epilogue: stage 32x128 bf16 band (pad stride 136),
      // re-read linear, store uint4 fully coalesced.
      uint16_t* dst = which ? kb : qb;
      float sc = which ? 1.f : QSC;
      uint16_t* EP = &As[0][0];  // reuse staging LDS (free after K-loop)
      int h2 = (bn & 7) * 2;     // two heads covered by this tile's 128 cols
      int rr = tid >> 3, cc0 = (tid & 7) * 16;
      int grow_base = bm * 128 + (rr >> 4) * 64 + (rr & 15);
      #pragma unroll
      for (int i = 0; i < 4; ++i) {
        #pragma unroll
        for (int j = 0; j < 4; ++j) {
          int col = wc * 64 + j * 16 + lr;
          float bv = bias[bn * 128 + col];
          #pragma unroll
          for (int r = 0; r < 4; ++r)
            EP[(wr * 16 + lg * 4 + r) * 136 + col] =
                f2bf((acc[i][j][r] + bv) * sc);
        }
        __syncthreads();
        int grow = grow_base + i * 16;
        int b = grow >> 11, t = grow & 2047;
        #pragma unroll
        for (int c = 0; c < 2; ++c) {
          int cc = cc0 + c * 8;
          int h = h2 + (cc >> 6), d = cc & 63;
          uint4 v = *(const uint4*)&EP[rr * 136 + cc];
          *(uint4*)&dst[((size_t)(b * 16 + h) * 2048 + t) * 64 + d] = v;
        }
        __syncthreads();
      }
    }
  }
}

// ---------------- flash attention, swapped-QK^T, no-max softmax ----------------
// (R14 verbatim) K staged with rx-swizzled gload_lds + koff reads; V arrives
// FRAGMENT-MAJOR and is staged as a LINEAR 8KB memcpy, read at f*512+lane*8.
// R8 stage-early + single __syncthreads double-buffer. p = exp2(s) no-max;
// pack via cvt_pk + permlane32_swap; O^T = V^T P^T, lane-local epilogue.
__global__ __launch_bounds__(256) void k_attn(const uint16_t* __restrict__ qb,
                                              const uint16_t* __restrict__ kb,
                                              const uint16_t* __restrict__ vfm,
                                              uint16_t* __restrict__ ob) {
  // SM: K0 @0, K1 @1, V0 @2, V1 @3 (each 8KB)
  __shared__ uint16_t SM[4][4096];
  int tid = threadIdx.x, lane = tid & 63, wid = tid >> 6;
  int l31 = lane & 31, hi = lane >> 5;
  int rx = (l31 & 7) ^ (((l31 >> 3) & 3) << 1);
  int bid = blockIdx.x;
  int bh = (bid & 7) * 8 + ((bid >> 3) & 7);
  int qt = bid >> 6;
  const uint16_t* qbh = qb + (size_t)bh * 2048 * 64;
  const uint16_t* kbh = kb + (size_t)bh * 2048 * 64;
  int q = qt * 128 + wid * 32 + l31;

  // K fragment byte-offsets in LDS (swizzled, R8-proven), hoisted
  uint32_t koff[8];
  #pragma unroll
  for (int kvt = 0; kvt < 2; ++kvt)
    #pragma unroll
    for (int ks = 0; ks < 4; ++ks)
      koff[kvt * 4 + ks] = (kvt * 32 + l31) * 128 + (((ks * 2 + hi) ^ rx) << 4);

  // Q frags: already scaled by 1/sqrt(D)*log2(e) in the QKV-GEMM epilogue
  bf16x8 qf[4];
  #pragma unroll
  for (int ks = 0; ks < 4; ++ks)
    qf[ks] = *(const bf16x8*)(qbh + (size_t)q * 64 + ks * 16 + hi * 8);

  f32x16 ovt[2] = {};
  f32x2 lr2 = {0.f, 0.f};

  // K staging (R8): rows of 128B = 8x16B slots; incremental pointers
  int r0 = tid >> 3;
  int sx = (tid & 7) ^ (r0 & 7) ^ (((r0 >> 3) & 3) << 1);  // same for r0 and r0+32
  const uint16_t* kp0 = kbh + (size_t)r0 * 64 + sx * 8;
  const uint16_t* kp1 = kbh + (size_t)(r0 + 32) * 64 + sx * 8;
  // V staging (R13): linear fragment-major, 1 tile = 4096 elems
  const uint16_t* vp = vfm + (size_t)bh * 131072 + tid * 8;

  auto stage = [&](int buf) {
    GLD_LDS(kp0, &SM[buf][wid * 512]);
    GLD_LDS(kp1, &SM[buf][2048 + wid * 512]);
    GLD_LDS(vp, &SM[2 + buf][wid * 512]);
    GLD_LDS(vp + 2048, &SM[2 + buf][2048 + wid * 512]);
    kp0 += 4096; kp1 += 4096; vp += 4096;
  };

  auto body = [&](int cur, bool dostage) {
    if (dostage) stage(cur ^ 1);
    const char* Kc = (const char*)SM + cur * 8192;
    const uint16_t* Vc = &SM[2 + cur][0];

    // S^T[kv][q]: A = K tile rows (swizzled read), B = Q frags. col(lane&31)=q.
    f32x16 sv[2] = {};
    __builtin_amdgcn_s_setprio(1);
    #pragma unroll
    for (int kvt = 0; kvt < 2; ++kvt)
      #pragma unroll
      for (int ks = 0; ks < 4; ++ks) {
        bf16x8 kf = *(const bf16x8*)(Kc + koff[kvt * 4 + ks]);
        sv[kvt] = __builtin_amdgcn_mfma_f32_32x32x16_bf16(kf, qf[ks], sv[kvt], 0, 0, 0);
      }
    __builtin_amdgcn_s_setprio(0);

    // p = exp2(s)
    #pragma unroll
    for (int t = 0; t < 2; ++t)
      #pragma unroll
      for (int r = 0; r < 16; ++r) sv[t][r] = __builtin_amdgcn_exp2f(sv[t][r]);

    // row-sum via packed-f32 tree on register-pair aliases (no copies)
    #define SVP(t, i) __builtin_shufflevector(sv[t], sv[t], 2 * (i), 2 * (i) + 1)
    f32x2 s0 = pkadd(pkadd(pkadd(SVP(0, 0), SVP(0, 1)), pkadd(SVP(0, 2), SVP(0, 3))),
                     pkadd(pkadd(SVP(0, 4), SVP(0, 5)), pkadd(SVP(0, 6), SVP(0, 7))));
    f32x2 s1 = pkadd(pkadd(pkadd(SVP(1, 0), SVP(1, 1)), pkadd(SVP(1, 2), SVP(1, 3))),
                     pkadd(pkadd(SVP(1, 4), SVP(1, 5)), pkadd(SVP(1, 6), SVP(1, 7))));
    #undef SVP
    lr2 = pkadd(lr2, pkadd(s0, s1));

    // pack P^T -> PV B-frags via cvt_pk + permlane32_swap (R6/R8-proven)
    union PB { uint32_t w[4]; bf16x8 v; } pb[4];
    #pragma unroll
    for (int t = 0; t < 2; ++t)
      #pragma unroll
      for (int s = 0; s < 2; ++s) {
        int rb = s * 8;
        #pragma unroll
        for (int i = 0; i < 2; ++i) {
          uint32_t a, b;
          asm("v_cvt_pk_bf16_f32 %0, %1, %2"
              : "=v"(a) : "v"(sv[t][rb + 2 * i]), "v"(sv[t][rb + 2 * i + 1]));
          asm("v_cvt_pk_bf16_f32 %0, %1, %2"
              : "=v"(b) : "v"(sv[t][rb + 4 + 2 * i]), "v"(sv[t][rb + 4 + 2 * i + 1]));
          asm("v_permlane32_swap_b32 %0, %1" : "+v"(a), "+v"(b));
          pb[2 * t + s].w[i] = a;
          pb[2 * t + s].w[2 + i] = b;
        }
      }

    // O^T[d][q] += V^T P^T : A = V fragments (linear conflict-free read)
    __builtin_amdgcn_s_setprio(1);
    #pragma unroll
    for (int dt = 0; dt < 2; ++dt)
      #pragma unroll
      for (int ks = 0; ks < 4; ++ks) {
        bf16x8 vf = *(const bf16x8*)&Vc[(dt * 4 + ks) * 512 + lane * 8];
        ovt[dt] = __builtin_amdgcn_mfma_f32_32x32x16_bf16(vf, pb[ks].v, ovt[dt], 0, 0, 0);
      }
    __builtin_amdgcn_s_setprio(0);

    __syncthreads();  // drains vmcnt: next tile landed during compute
  };

  stage(0);
  __syncthreads();
  for (int t = 0; t < 30; t += 2) {
    body(0, true);
    body(1, true);
  }
  body(0, true);
  body(1, false);

  // epilogue: O^T col = q is lane-local
  float lrow = lr2.x + lr2.y;
  lrow += __shfl_xor(lrow, 32);
  float inv = 1.f / lrow;
  int b = bh >> 4, h = bh & 15;
  size_t base = ((size_t)b * 2048 + q) * 1024 + h * 64;
  #pragma unroll
  for (int dt = 0; dt < 2; ++dt)
    #pragma unroll
    for (int r = 0; r < 16; r += 2) {
      int d = dt * 32 + (r & 3) + 8 * (r >> 2) + 4 * hi;
      uint32_t w = (uint32_t)f2bf(ovt[dt][r] * inv) |
                   ((uint32_t)f2bf(ovt[dt][r + 1] * inv) << 16);
      *(uint32_t*)&ob[base + d] = w;
    }
}

extern "C" void kernel_launch(void* const* d_in, const int* in_sizes, int n_in,
                              void* d_out, int out_size, void* d_ws,
                              size_t ws_size, hipStream_t stream) {
  const float* x = (const float*)d_in[0];
  const float* Wqkv = (const float*)d_in[1];
  const float* bqkv = (const float*)d_in[2];
  const float* Wproj = (const float*)d_in[3];
  const float* bproj = (const float*)d_in[4];
  float* out = (float*)d_out;
  char* ws = (char*)d_ws;

  uint16_t* xb = (uint16_t*)(ws);                       // 16 MB (reused as ob)
  uint16_t* wqkvt = (uint16_t*)(ws + (16ull << 20));    // 6 MB
  uint16_t* wprojt = (uint16_t*)(ws + (22ull << 20));   // 2 MB
  uint16_t* qbuf = (uint16_t*)(ws + (24ull << 20));     // 16 MB
  uint16_t* kbuf = (uint16_t*)(ws + (40ull << 20));     // 16 MB (row-major)
  uint16_t* vtb = (uint16_t*)(ws + (56ull << 20));      // 16 MB (fragment-major)
  uint16_t* ob = xb;  // x no longer needed after QKV GEMM

  k_prep<<<8192, 256, 0, stream>>>(x, Wqkv, Wproj, xb, wqkvt, wprojt);
  k_gemm<0><<<dim3(64, 24), 256, 0, stream>>>(xb, wqkvt, bqkv, nullptr, 3072,
                                              qbuf, kbuf, vtb);
  k_attn<<<1024, 256, 0, stream>>>(qbuf, kbuf, vtb, ob);
  k_gemm<1><<<dim3(64, 8), 256, 0, stream>>>(ob, wprojt, bproj, out, 1024,
                                             nullptr, nullptr, nullptr);
}

// Round 16
// 194.443 us; speedup vs baseline: 1.0447x; 1.0447x over previous
//
#include <hip/hip_runtime.h>
#include <stdint.h>

#define DEV __device__ __forceinline__

typedef __bf16 bf16x8 __attribute__((ext_vector_type(8)));
typedef float f32x2 __attribute__((ext_vector_type(2)));
typedef float f32x4 __attribute__((ext_vector_type(4)));
typedef float f32x16 __attribute__((ext_vector_type(16)));

DEV uint16_t f2bf(float f) {
  union { float f; uint32_t u; } v; v.f = f;
  return (uint16_t)((v.u + 0x7FFFu + ((v.u >> 16) & 1u)) >> 16);
}

DEV f32x2 pkadd(f32x2 a, f32x2 b) {
  f32x2 d;
  asm("v_pk_add_f32 %0, %1, %2" : "=v"(d) : "v"(a), "v"(b));
  return d;
}

// async global->LDS, 16B per lane; LDS dest must be wave-uniform base
#define GLD_LDS(gsrc, ldst)                                                   \
  __builtin_amdgcn_global_load_lds(                                           \
      (__attribute__((address_space(1))) void*)(void*)(gsrc),                 \
      (__attribute__((address_space(3))) void*)(ldst), 16, 0, 0)

// ---------------- fused prep: x->bf16 + both W transposes ----------------
__global__ __launch_bounds__(256) void k_prep(const float* __restrict__ x,
                                              const float* __restrict__ Wqkv,
                                              const float* __restrict__ Wproj,
                                              uint16_t* __restrict__ xb,
                                              uint16_t* __restrict__ wqkvt,
                                              uint16_t* __restrict__ wprojt) {
  __shared__ float tile[32][33];
  int bid = blockIdx.x;
  if (bid < 4096) {
    int i = bid * 256 + threadIdx.x;
    const float4* p = (const float4*)x;
    float4 a = p[i * 2], b = p[i * 2 + 1];
    union { uint16_t s[8]; uint4 v; } o;
    o.s[0] = f2bf(a.x); o.s[1] = f2bf(a.y); o.s[2] = f2bf(a.z); o.s[3] = f2bf(a.w);
    o.s[4] = f2bf(b.x); o.s[5] = f2bf(b.y); o.s[6] = f2bf(b.z); o.s[7] = f2bf(b.w);
    ((uint4*)xb)[i] = o.v;
    return;
  }
  const float* in;
  uint16_t* out;
  int n0, k0, Ncols;
  if (bid < 7168) {
    int local = bid - 4096;
    in = Wqkv; out = wqkvt; Ncols = 3072;
    n0 = (local % 96) * 32; k0 = (local / 96) * 32;
  } else {
    int local = bid - 7168;
    in = Wproj; out = wprojt; Ncols = 1024;
    n0 = (local % 32) * 32; k0 = (local / 32) * 32;
  }
  int tx = threadIdx.x & 31, ty = threadIdx.x >> 5;  // 8 rows of 32
  #pragma unroll
  for (int r = ty; r < 32; r += 8)
    tile[r][tx] = in[(size_t)(k0 + r) * Ncols + n0 + tx];
  __syncthreads();
  #pragma unroll
  for (int r = ty; r < 32; r += 8)
    out[(size_t)(n0 + r) * 1024 + k0 + tx] = f2bf(tile[tx][r]);
}

// ---------------- bf16 GEMM: C[M,N] = A[M,K=1024] * BT[N,K]^T + bias ----------------
// (R8 structure) 2-phase double-buffered: stage ks+1 BEFORE compute of ks;
// ONE __syncthreads per K-step. 2-D grid.
// MODE 0 epilogue (R12-proven): Q pre-scaled + K row-major [bh][t][64];
// V FRAGMENT-MAJOR vtb[bh*131072 + kt*4096 + f*512 + lane*8 + e] (uint2 stores,
// and attn stages V tiles as linear memcpys -> conflict-free LDS reads).
template <int MODE>
__global__ __launch_bounds__(256) void k_gemm(
    const uint16_t* __restrict__ A, const uint16_t* __restrict__ BT,
    const float* __restrict__ bias, float* __restrict__ fout, int Ndim,
    uint16_t* __restrict__ qb, uint16_t* __restrict__ kb,
    uint16_t* __restrict__ vtb) {
  __shared__ uint16_t As[2][128 * 32];
  __shared__ uint16_t Bs[2][128 * 32];
  const int K = 1024;
  int tid = threadIdx.x;
  int lane = tid & 63, wid = tid >> 6;
  int lg = lane >> 4, lr = lane & 15;
  int wr = wid >> 1, wc = wid & 1;
  int bm = blockIdx.x, bn = blockIdx.y;

  int c0 = tid, c1 = tid + 256;
  int r0 = c0 >> 2, sl0 = (c0 & 3) ^ (r0 & 3);
  int r1 = c1 >> 2, sl1 = (c1 & 3) ^ (r1 & 3);
  const uint16_t* gA0 = A + (size_t)(bm * 128 + r0) * K + sl0 * 8;
  const uint16_t* gA1 = A + (size_t)(bm * 128 + r1) * K + sl1 * 8;
  const uint16_t* gB0 = BT + (size_t)(bn * 128 + r0) * K + sl0 * 8;
  const uint16_t* gB1 = BT + (size_t)(bn * 128 + r1) * K + sl1 * 8;

  uint32_t aoff[4], boff[4];
  #pragma unroll
  for (int i = 0; i < 4; ++i) {
    int rowa = wr * 64 + i * 16 + lr;
    aoff[i] = rowa * 64 + ((lg ^ (rowa & 3)) << 4);
    int rowb = wc * 64 + i * 16 + lr;
    boff[i] = rowb * 64 + ((lg ^ (rowb & 3)) << 4);
  }

  f32x4 acc[4][4] = {};

  auto stageg = [&](int buf) {
    GLD_LDS(gA0, &As[buf][wid * 512]);
    GLD_LDS(gA1, &As[buf][2048 + wid * 512]);
    GLD_LDS(gB0, &Bs[buf][wid * 512]);
    GLD_LDS(gB1, &Bs[buf][2048 + wid * 512]);
    gA0 += 32; gA1 += 32; gB0 += 32; gB1 += 32;
  };

  auto gbody = [&](int cur, bool dostage) {
    if (dostage) stageg(cur ^ 1);
    const char* Ab = (const char*)As + cur * 8192;
    const char* Bb = (const char*)Bs + cur * 8192;
    bf16x8 af[4], bfv[4];
    #pragma unroll
    for (int i = 0; i < 4; ++i) af[i] = *(const bf16x8*)(Ab + aoff[i]);
    #pragma unroll
    for (int j = 0; j < 4; ++j) bfv[j] = *(const bf16x8*)(Bb + boff[j]);
    __builtin_amdgcn_s_setprio(1);
    #pragma unroll
    for (int i = 0; i < 4; ++i)
      #pragma unroll
      for (int j = 0; j < 4; ++j)
        acc[i][j] = __builtin_amdgcn_mfma_f32_16x16x32_bf16(af[i], bfv[j],
                                                            acc[i][j], 0, 0, 0);
    __builtin_amdgcn_s_setprio(0);
    __syncthreads();
  };

  stageg(0);
  __syncthreads();
  for (int ks = 0; ks < 30; ks += 2) {
    gbody(0, true);
    gbody(1, true);
  }
  gbody(0, true);
  gbody(1, false);

  int m0 = bm * 128 + wr * 64;
  int n0 = bn * 128 + wc * 64;
  if (MODE == 1) {
    #pragma unroll
    for (int i = 0; i < 4; ++i) {
      int row = m0 + i * 16 + lg * 4;
      #pragma unroll
      for (int j = 0; j < 4; ++j) {
        int col = n0 + j * 16 + lr;
        float bv = bias[col];
        #pragma unroll
        for (int r = 0; r < 4; ++r)
          fout[(size_t)(row + r) * Ndim + col] = acc[i][j][r] + bv;
      }
    }
  } else {
    const float QSC = 0.18033688011112042f;  // 1/sqrt(64) * log2(e)
    #pragma unroll
    for (int i = 0; i < 4; ++i) {
      int rowb = m0 + i * 16 + lg * 4;
      int b = rowb >> 11, t = rowb & 2047;  // t multiple of 4
      #pragma unroll
      for (int j = 0; j < 4; ++j) {
        int colb = n0 + j * 16 + lr;
        int which = colb >> 10;
        int hd = colb & 1023;
        int h = hd >> 6, d = hd & 63;
        float bv = bias[colb];
        size_t bh = (size_t)(b * 16 + h);
        if (which == 2) {
          // fragment-major V (R12-proven): tile t>>6, frag (d>>5)*4+((t>>4)&3),
          // lane ((t>>3)&1)*32+(d&31), elems (t&7)+r (contiguous -> uint2)
          union { uint16_t s[4]; uint2 v; } pk;
          #pragma unroll
          for (int r = 0; r < 4; ++r) pk.s[r] = f2bf(acc[i][j][r] + bv);
          size_t vidx = bh * 131072 + (size_t)(t >> 6) * 4096 +
                        (size_t)((d >> 5) * 4 + ((t >> 4) & 3)) * 512 +
                        (size_t)((((t >> 3) & 1) * 32 + (d & 31)) * 8) + (t & 7);
          *(uint2*)&vtb[vidx] = pk.v;
        } else if (which == 1) {
          // K row-major (R8/R12-proven)
          #pragma unroll
          for (int r = 0; r < 4; ++r)
            kb[(bh * 2048 + t + r) * 64 + d] = f2bf(acc[i][j][r] + bv);
        } else {
          #pragma unroll
          for (int r = 0; r < 4; ++r)
            qb[(bh * 2048 + t + r) * 64 + d] = f2bf((acc[i][j][r] + bv) * QSC);
        }
      }
    }
  }
}

// ---------------- flash attention, swapped-QK^T, no-max softmax ----------------
// (R14 verbatim) K staged with rx-swizzled gload_lds + koff reads; V arrives
// FRAGMENT-MAJOR and is staged as a LINEAR 8KB memcpy, read at f*512+lane*8.
// R8 stage-early + single __syncthreads double-buffer. p = exp2(s) no-max;
// pack via cvt_pk + permlane32_swap; O^T = V^T P^T, lane-local epilogue.
__global__ __launch_bounds__(256) void k_attn(const uint16_t* __restrict__ qb,
                                              const uint16_t* __restrict__ kb,
                                              const uint16_t* __restrict__ vfm,
                                              uint16_t* __restrict__ ob) {
  // SM: K0 @0, K1 @1, V0 @2, V1 @3 (each 8KB)
  __shared__ uint16_t SM[4][4096];
  int tid = threadIdx.x, lane = tid & 63, wid = tid >> 6;
  int l31 = lane & 31, hi = lane >> 5;
  int rx = (l31 & 7) ^ (((l31 >> 3) & 3) << 1);
  int bid = blockIdx.x;
  int bh = (bid & 7) * 8 + ((bid >> 3) & 7);
  int qt = bid >> 6;
  const uint16_t* qbh = qb + (size_t)bh * 2048 * 64;
  const uint16_t* kbh = kb + (size_t)bh * 2048 * 64;
  int q = qt * 128 + wid * 32 + l31;

  // K fragment byte-offsets in LDS (swizzled, R8-proven), hoisted
  uint32_t koff[8];
  #pragma unroll
  for (int kvt = 0; kvt < 2; ++kvt)
    #pragma unroll
    for (int ks = 0; ks < 4; ++ks)
      koff[kvt * 4 + ks] = (kvt * 32 + l31) * 128 + (((ks * 2 + hi) ^ rx) << 4);

  // Q frags: already scaled by 1/sqrt(D)*log2(e) in the QKV-GEMM epilogue
  bf16x8 qf[4];
  #pragma unroll
  for (int ks = 0; ks < 4; ++ks)
    qf[ks] = *(const bf16x8*)(qbh + (size_t)q * 64 + ks * 16 + hi * 8);

  f32x16 ovt[2] = {};
  f32x2 lr2 = {0.f, 0.f};

  // K staging (R8): rows of 128B = 8x16B slots; incremental pointers
  int r0 = tid >> 3;
  int sx = (tid & 7) ^ (r0 & 7) ^ (((r0 >> 3) & 3) << 1);  // same for r0 and r0+32
  const uint16_t* kp0 = kbh + (size_t)r0 * 64 + sx * 8;
  const uint16_t* kp1 = kbh + (size_t)(r0 + 32) * 64 + sx * 8;
  // V staging (R13): linear fragment-major, 1 tile = 4096 elems
  const uint16_t* vp = vfm + (size_t)bh * 131072 + tid * 8;

  auto stage = [&](int buf) {
    GLD_LDS(kp0, &SM[buf][wid * 512]);
    GLD_LDS(kp1, &SM[buf][2048 + wid * 512]);
    GLD_LDS(vp, &SM[2 + buf][wid * 512]);
    GLD_LDS(vp + 2048, &SM[2 + buf][2048 + wid * 512]);
    kp0 += 4096; kp1 += 4096; vp += 4096;
  };

  auto body = [&](int cur, bool dostage) {
    if (dostage) stage(cur ^ 1);
    const char* Kc = (const char*)SM + cur * 8192;
    const uint16_t* Vc = &SM[2 + cur][0];

    // S^T[kv][q]: A = K tile rows (swizzled read), B = Q frags. col(lane&31)=q.
    f32x16 sv[2] = {};
    __builtin_amdgcn_s_setprio(1);
    #pragma unroll
    for (int kvt = 0; kvt < 2; ++kvt)
      #pragma unroll
      for (int ks = 0; ks < 4; ++ks) {
        bf16x8 kf = *(const bf16x8*)(Kc + koff[kvt * 4 + ks]);
        sv[kvt] = __builtin_amdgcn_mfma_f32_32x32x16_bf16(kf, qf[ks], sv[kvt], 0, 0, 0);
      }
    __builtin_amdgcn_s_setprio(0);

    // p = exp2(s)
    #pragma unroll
    for (int t = 0; t < 2; ++t)
      #pragma unroll
      for (int r = 0; r < 16; ++r) sv[t][r] = __builtin_amdgcn_exp2f(sv[t][r]);

    // row-sum via packed-f32 tree on register-pair aliases (no copies)
    #define SVP(t, i) __builtin_shufflevector(sv[t], sv[t], 2 * (i), 2 * (i) + 1)
    f32x2 s0 = pkadd(pkadd(pkadd(SVP(0, 0), SVP(0, 1)), pkadd(SVP(0, 2), SVP(0, 3))),
                     pkadd(pkadd(SVP(0, 4), SVP(0, 5)), pkadd(SVP(0, 6), SVP(0, 7))));
    f32x2 s1 = pkadd(pkadd(pkadd(SVP(1, 0), SVP(1, 1)), pkadd(SVP(1, 2), SVP(1, 3))),
                     pkadd(pkadd(SVP(1, 4), SVP(1, 5)), pkadd(SVP(1, 6), SVP(1, 7))));
    #undef SVP
    lr2 = pkadd(lr2, pkadd(s0, s1));

    // pack P^T -> PV B-frags via cvt_pk + permlane32_swap (R6/R8-proven)
    union PB { uint32_t w[4]; bf16x8 v; } pb[4];
    #pragma unroll
    for (int t = 0; t < 2; ++t)
      #pragma unroll
      for (int s = 0; s < 2; ++s) {
        int rb = s * 8;
        #pragma unroll
        for (int i = 0; i < 2; ++i) {
          uint32_t a, b;
          asm("v_cvt_pk_bf16_f32 %0, %1, %2"
              : "=v"(a) : "v"(sv[t][rb + 2 * i]), "v"(sv[t][rb + 2 * i + 1]));
          asm("v_cvt_pk_bf16_f32 %0, %1, %2"
              : "=v"(b) : "v"(sv[t][rb + 4 + 2 * i]), "v"(sv[t][rb + 4 + 2 * i + 1]));
          asm("v_permlane32_swap_b32 %0, %1" : "+v"(a), "+v"(b));
          pb[2 * t + s].w[i] = a;
          pb[2 * t + s].w[2 + i] = b;
        }
      }

    // O^T[d][q] += V^T P^T : A = V fragments (linear conflict-free read)
    __builtin_amdgcn_s_setprio(1);
    #pragma unroll
    for (int dt = 0; dt < 2; ++dt)
      #pragma unroll
      for (int ks = 0; ks < 4; ++ks) {
        bf16x8 vf = *(const bf16x8*)&Vc[(dt * 4 + ks) * 512 + lane * 8];
        ovt[dt] = __builtin_amdgcn_mfma_f32_32x32x16_bf16(vf, pb[ks].v, ovt[dt], 0, 0, 0);
      }
    __builtin_amdgcn_s_setprio(0);

    __syncthreads();  // drains vmcnt: next tile landed during compute
  };

  stage(0);
  __syncthreads();
  for (int t = 0; t < 30; t += 2) {
    body(0, true);
    body(1, true);
  }
  body(0, true);
  body(1, false);

  // epilogue: O^T col = q is lane-local
  float lrow = lr2.x + lr2.y;
  lrow += __shfl_xor(lrow, 32);
  float inv = 1.f / lrow;
  int b = bh >> 4, h = bh & 15;
  size_t base = ((size_t)b * 2048 + q) * 1024 + h * 64;
  #pragma unroll
  for (int dt = 0; dt < 2; ++dt)
    #pragma unroll
    for (int r = 0; r < 16; r += 2) {
      int d = dt * 32 + (r & 3) + 8 * (r >> 2) + 4 * hi;
      uint32_t w = (uint32_t)f2bf(ovt[dt][r] * inv) |
                   ((uint32_t)f2bf(ovt[dt][r + 1] * inv) << 16);
      *(uint32_t*)&ob[base + d] = w;
    }
}

extern "C" void kernel_launch(void* const* d_in, const int* in_sizes, int n_in,
                              void* d_out, int out_size, void* d_ws,
                              size_t ws_size, hipStream_t stream) {
  const float* x = (const float*)d_in[0];
  const float* Wqkv = (const float*)d_in[1];
  const float* bqkv = (const float*)d_in[2];
  const float* Wproj = (const float*)d_in[3];
  const float* bproj = (const float*)d_in[4];
  float* out = (float*)d_out;
  char* ws = (char*)d_ws;

  uint16_t* xb = (uint16_t*)(ws);                       // 16 MB (reused as ob)
  uint16_t* wqkvt = (uint16_t*)(ws + (16ull << 20));    // 6 MB
  uint16_t* wprojt = (uint16_t*)(ws + (22ull << 20));   // 2 MB
  uint16_t* qbuf = (uint16_t*)(ws + (24ull << 20));     // 16 MB
  uint16_t* kbuf = (uint16_t*)(ws + (40ull << 20));     // 16 MB (row-major)
  uint16_t* vtb = (uint16_t*)(ws + (56ull << 20));      // 16 MB (fragment-major)
  uint16_t* ob = xb;  // x no longer needed after QKV GEMM

  k_prep<<<8192, 256, 0, stream>>>(x, Wqkv, Wproj, xb, wqkvt, wprojt);
  k_gemm<0><<<dim3(64, 24), 256, 0, stream>>>(xb, wqkvt, bqkv, nullptr, 3072,
                                              qbuf, kbuf, vtb);
  k_attn<<<1024, 256, 0, stream>>>(qbuf, kbuf, vtb, ob);
  k_gemm<1><<<dim3(64, 8), 256, 0, stream>>>(ob, wprojt, bproj, out, 1024,
                                             nullptr, nullptr, nullptr);
}